// Round 3
// baseline (545.400 us; speedup 1.0000x reference)
//
#include <hip/hip_runtime.h>
#include <hip/hip_bf16.h>

// PositionalEncoding: out[b,c,w1,w2,t] = x[b,c,w1,w2,t] + pe[c,t]
//   pe[c,t] = (c even) ? sin(inv_freq[c]*t) : cos(inv_freq[c]*t)
//   inv_freq[c] = 10000^(-2*(c/2)/C)
// Shapes: B=4, C=64, W=128, T=20  -> 83,886,080 fp32 elements.
// Memory-bound: ~671 MB traffic -> ~106 us roofline.

#define C_DIM 64
#define T_DIM 20
#define CSTRIDE (128 * 128 * 20)   // W*W*T = 327680 elements per channel slab
#define NELEM (4 * 64 * 128 * 128 * 20)
#define NV4 (NELEM / 4)            // 20,971,520 float4s

__global__ __launch_bounds__(256) void pe_add_kernel(const float* __restrict__ x,
                                                     float* __restrict__ out) {
    // --- build the 64x20 PE table in LDS (5 KB) ---
    __shared__ float pe[C_DIM * T_DIM];
    for (int idx = threadIdx.x; idx < C_DIM * T_DIM; idx += blockDim.x) {
        int c = idx / T_DIM;
        int t = idx - c * T_DIM;
        // inv_freq = 10000^(-2*(c/2)/64)
        float invf = __powf(10000.0f, -2.0f * (float)(c >> 1) * (1.0f / 64.0f));
        float ang = invf * (float)t;
        pe[idx] = (c & 1) ? cosf(ang) : sinf(ang);
    }
    __syncthreads();

    const float4* __restrict__ x4 = (const float4*)x;
    float4* __restrict__ o4 = (float4*)out;

    unsigned stride = gridDim.x * blockDim.x;
    for (unsigned v = blockIdx.x * blockDim.x + threadIdx.x; v < (unsigned)NV4; v += stride) {
        unsigned i = v * 4u;                     // flat element index
        unsigned t0 = i % (unsigned)T_DIM;       // 20 | 4 -> float4 never crosses a row
        unsigned c = (i / (unsigned)CSTRIDE) & (C_DIM - 1);
        // pe row chunk: c*20 + t0, t0 in {0,4,8,12,16} -> 16B aligned
        float4 p = *(const float4*)&pe[c * T_DIM + t0];
        float4 xv = x4[v];
        float4 r;
        r.x = xv.x + p.x;
        r.y = xv.y + p.y;
        r.z = xv.z + p.z;
        r.w = xv.w + p.w;
        o4[v] = r;
    }
}

extern "C" void kernel_launch(void* const* d_in, const int* in_sizes, int n_in,
                              void* d_out, int out_size, void* d_ws, size_t ws_size,
                              hipStream_t stream) {
    const float* x = (const float*)d_in[0];
    float* out = (float*)d_out;

    const int block = 256;
    // memory-bound: cap grid and grid-stride (G11)
    int grid = 2048;
    pe_add_kernel<<<grid, block, 0, stream>>>(x, out);
}